// Round 3
// baseline (246.052 us; speedup 1.0000x reference)
//
#include <hip/hip_runtime.h>
#include <math.h>

typedef __attribute__((ext_vector_type(8))) short short8;
typedef __attribute__((ext_vector_type(4))) float f32x4;
typedef __attribute__((ext_vector_type(4))) unsigned short us4;

constexpr int NSEG = 16;
constexpr int CC   = 768;
constexpr int PP   = 197;
constexpr int NH   = 12;
constexpr int HD   = 64;
constexpr int NT   = 512;
constexpr int MN   = NT * CC;
constexpr float LN_EPS = 1e-5f;

// pass-through copy geometry in float4 units (p>=1 rows of every token)
constexpr unsigned CPT  = 196 * CC / 4;          // 37632
constexpr unsigned TOK4 = PP * CC / 4;           // 37824
constexpr unsigned ROW4 = CC / 4;                // 192
constexpr unsigned W4TOT = (unsigned)NT * CPT;   // 19267584

__device__ inline unsigned short f2bf(float f) {
    unsigned u = __float_as_uint(f);
    u += 0x7fffu + ((u >> 16) & 1u);
    return (unsigned short)(u >> 16);
}

__device__ inline unsigned cidx(unsigned i) {
    unsigned t = i / CPT;                 // magic-mul
    return i + t * ROW4 + ROW4;           // == t*TOK4 + ROW4 + (i - t*CPT)
}

// 4-deep unrolled copy: 4 loads in flight before the stores (MLP)
__device__ inline void copy_slice(const float* __restrict__ xf, float* __restrict__ of,
                                  unsigned start, unsigned end,
                                  unsigned gt, unsigned nth) {
    const float4* __restrict__ x4 = (const float4*)xf;
    float4* __restrict__ o4 = (float4*)of;
    unsigned i = start + gt;
    unsigned s1 = nth, s2 = 2 * nth, s3 = 3 * nth, s4 = 4 * nth;
    for (; i + s3 < end; i += s4) {
        unsigned a0 = cidx(i), a1 = cidx(i + s1), a2 = cidx(i + s2), a3 = cidx(i + s3);
        float4 v0 = x4[a0];
        float4 v1 = x4[a1];
        float4 v2 = x4[a2];
        float4 v3 = x4[a3];
        o4[a0] = v0; o4[a1] = v1; o4[a2] = v2; o4[a3] = v3;
    }
    for (; i < end; i += s1) { unsigned a = cidx(i); o4[a] = x4[a]; }
}

// ---------------- 64x64 MFMA bf16 tile, 4 waves, fragments direct from global ----------------
__device__ inline void gemm_tile(const unsigned short* __restrict__ A,   // NTxCC bf16
                                 const unsigned short* __restrict__ Bt,  // CCxCC bf16 [n][k]
                                 const float* __restrict__ bias,
                                 float* __restrict__ outp,
                                 int by, int bx) {
    int tid  = threadIdx.x;
    int lane = tid & 63, wv = tid >> 6;
    int wr = wv >> 1, wc = wv & 1;
    int l15 = lane & 15, lh = lane >> 4;
    int m0 = by * 64 + wr * 32;
    int n0 = bx * 64 + wc * 32;
    f32x4 acc[2][2] = {};
    const unsigned short* Ar0 = A  + (size_t)(m0 + l15) * CC + lh * 8;
    const unsigned short* Ar1 = Ar0 + 16 * CC;
    const unsigned short* Br0 = Bt + (size_t)(n0 + l15) * CC + lh * 8;
    const unsigned short* Br1 = Br0 + 16 * CC;
    #pragma unroll 4
    for (int k0 = 0; k0 < CC; k0 += 32) {
        short8 a0 = *(const short8*)(Ar0 + k0);
        short8 a1 = *(const short8*)(Ar1 + k0);
        short8 b0 = *(const short8*)(Br0 + k0);
        short8 b1 = *(const short8*)(Br1 + k0);
        acc[0][0] = __builtin_amdgcn_mfma_f32_16x16x32_bf16(a0, b0, acc[0][0], 0, 0, 0);
        acc[0][1] = __builtin_amdgcn_mfma_f32_16x16x32_bf16(a0, b1, acc[0][1], 0, 0, 0);
        acc[1][0] = __builtin_amdgcn_mfma_f32_16x16x32_bf16(a1, b0, acc[1][0], 0, 0, 0);
        acc[1][1] = __builtin_amdgcn_mfma_f32_16x16x32_bf16(a1, b1, acc[1][1], 0, 0, 0);
    }
    #pragma unroll
    for (int mf = 0; mf < 2; ++mf)
        #pragma unroll
        for (int nf = 0; nf < 2; ++nf)
            #pragma unroll
            for (int r = 0; r < 4; ++r) {
                int row = m0 + mf * 16 + lh * 4 + r;
                int col = n0 + nf * 16 + l15;
                outp[(size_t)row * CC + col] = acc[mf][nf][r] + bias[col];
            }
}

// ================= K1: copy (1536) | shift+LN (512) | weight cvt (2304) =================
constexpr int K1_CPY = 1536, K1_LN = NT, K1_CVT = 2304;
__global__ __launch_bounds__(256) void k1(const float* __restrict__ x, const float* __restrict__ w1,
        const float* __restrict__ g, const float* __restrict__ bln,
        const float* __restrict__ Wq, const float* __restrict__ Wk,
        const float* __restrict__ Wv, const float* __restrict__ Wo,
        float* __restrict__ s_shift, unsigned short* __restrict__ tln,
        unsigned short* __restrict__ wt, float* __restrict__ out,
        unsigned cstart, unsigned cend) {
    __shared__ float smem[32 * 33];
    int bid = blockIdx.x, tid = threadIdx.x;
    if (bid < K1_CPY) {
        copy_slice(x, out, cstart, cend, (unsigned)bid * 256 + tid, K1_CPY * 256);
    } else if (bid < K1_CPY + K1_LN) {
        int r = bid - K1_CPY, seg = r & (NSEG - 1);
        float vals[3]; float local = 0.f;
        #pragma unroll
        for (int i = 0; i < 3; ++i) {
            int c = tid + i * 256;
            float v = x[(size_t)r * PP * CC + c];
            if (seg > 0) v += w1[c] * x[(size_t)(r - 1) * PP * CC + c];
            vals[i] = v; local += v;
        }
        smem[tid] = local; __syncthreads();
        for (int off = 128; off > 0; off >>= 1) {
            if (tid < off) smem[tid] += smem[tid + off];
            __syncthreads();
        }
        float mu = smem[0] * (1.0f / CC); __syncthreads();
        float lv = 0.f;
        #pragma unroll
        for (int i = 0; i < 3; ++i) { float d = vals[i] - mu; lv += d * d; }
        smem[tid] = lv; __syncthreads();
        for (int off = 128; off > 0; off >>= 1) {
            if (tid < off) smem[tid] += smem[tid + off];
            __syncthreads();
        }
        float rstd = rsqrtf(smem[0] * (1.0f / CC) + LN_EPS);
        #pragma unroll
        for (int i = 0; i < 3; ++i) {
            int c = tid + i * 256;
            s_shift[(size_t)r * CC + c] = vals[i];
            tln[(size_t)r * CC + c] = f2bf((vals[i] - mu) * rstd * g[c] + bln[c]);
        }
    } else {
        int idx = bid - K1_CPY - K1_LN;
        int mat = idx / 576, tile = idx % 576;
        int tr = tile / 24, tc = tile % 24;
        const float* W = mat == 0 ? Wq : mat == 1 ? Wk : mat == 2 ? Wv : Wo;
        int lr = tid >> 3, lc = (tid & 7) * 4;
        float4 v = *(const float4*)(W + (size_t)(tr * 32 + lr) * CC + tc * 32 + lc);
        smem[lr * 33 + lc + 0] = v.x; smem[lr * 33 + lc + 1] = v.y;
        smem[lr * 33 + lc + 2] = v.z; smem[lr * 33 + lc + 3] = v.w;
        __syncthreads();
        int ln_ = tid >> 3, kc = (tid & 7) * 4;
        us4 o;
        #pragma unroll
        for (int j = 0; j < 4; ++j) o[j] = f2bf(smem[(kc + j) * 33 + ln_]);
        *(us4*)(wt + (size_t)mat * CC * CC + (size_t)(tc * 32 + ln_) * CC + tr * 32 + kc) = o;
    }
}

// ================= K2: copy (1792) | QKV MFMA GEMM (288) =================
constexpr int K2_CPY = 1792, K2_GEMM = 288;
__global__ __launch_bounds__(256) void k2(const unsigned short* __restrict__ tln,
        const unsigned short* __restrict__ wt,
        const float* __restrict__ bq, const float* __restrict__ bk, const float* __restrict__ bv,
        float* __restrict__ qkv,
        const float* __restrict__ x, float* __restrict__ out,
        unsigned cstart, unsigned cend) {
    int bid = blockIdx.x, tid = threadIdx.x;
    if (bid < K2_CPY) {
        copy_slice(x, out, cstart, cend, (unsigned)bid * 256 + tid, K2_CPY * 256);
    } else {
        int idx = bid - K2_CPY;
        int z = idx / 96, rem = idx % 96;
        int by = rem / 12, bx = rem % 12;
        const float* bias = z == 0 ? bq : (z == 1 ? bk : bv);
        gemm_tile(tln, wt + (size_t)z * CC * CC, bias, qkv + (size_t)z * MN, by, bx);
    }
}

// ================= K3: copy (1792) | fused attn + O-proj per batch (32) =================
constexpr int K3_CPY = 1792, K3_FUSE = 32;
__global__ __launch_bounds__(256) void k3(const float* __restrict__ qkv,
        const unsigned short* __restrict__ wto,
        const float* __restrict__ bo, const float* __restrict__ s_shift,
        unsigned short* __restrict__ ctxg,
        float* __restrict__ out, const float* __restrict__ x,
        unsigned cstart, unsigned cend) {
    __shared__ float qs[16][68], ks[16][68], vs[16][68];   // 13 KB
    __shared__ float sc[16][17];
    __shared__ float rsum[16];
    int bid = blockIdx.x, tid = threadIdx.x;
    if (bid < K3_CPY) {
        copy_slice(x, out, cstart, cend, (unsigned)bid * 256 + tid, K3_CPY * 256);
        return;
    }
    int bb = bid - K3_CPY;                 // batch 0..31
    const float* qp = qkv;
    const float* kp = qkv + MN;
    const float* vp = qkv + 2 * MN;
    int row = tid >> 4, c4 = tid & 15;     // 16 rows x 16 float4-cols

    for (int h = 0; h < NH; ++h) {
        size_t base = (size_t)(bb * NSEG + row) * CC + h * HD + c4 * 4;
        float4 q4 = *(const float4*)(qp + base);
        float4 k4 = *(const float4*)(kp + base);
        float4 v4 = *(const float4*)(vp + base);
        *(float4*)&qs[row][c4 * 4] = q4;
        *(float4*)&ks[row][c4 * 4] = k4;
        *(float4*)&vs[row][c4 * 4] = v4;
        __syncthreads();
        {   // scores: thread (t,s)
            int t = tid >> 4, s = tid & 15;
            float acc = 0.f;
            #pragma unroll
            for (int d0 = 0; d0 < HD; d0 += 4) {
                float4 qv = *(const float4*)&qs[t][d0];
                float4 kv = *(const float4*)&ks[s][d0];
                acc += qv.x * kv.x + qv.y * kv.y + qv.z * kv.z + qv.w * kv.w;
            }
            sc[t][s] = acc * 0.125f;
        }
        __syncthreads();
        if (tid < 16) {
            float m = -1e30f;
            #pragma unroll
            for (int s = 0; s < 16; ++s) m = fmaxf(m, sc[tid][s]);
            float su = 0.f;
            #pragma unroll
            for (int s = 0; s < 16; ++s) { float e = __expf(sc[tid][s] - m); sc[tid][s] = e; su += e; }
            rsum[tid] = su;
        }
        __syncthreads();
        {   // PV: thread (t, c4) -> 4 dims
            float4 o = {0.f, 0.f, 0.f, 0.f};
            #pragma unroll
            for (int ss = 0; ss < 16; ++ss) {
                float p = sc[row][ss];
                float4 vv = *(const float4*)&vs[ss][c4 * 4];
                o.x += p * vv.x; o.y += p * vv.y; o.z += p * vv.z; o.w += p * vv.w;
            }
            float inv = 1.f / rsum[row];
            us4 ob;
            ob[0] = f2bf(o.x * inv); ob[1] = f2bf(o.y * inv);
            ob[2] = f2bf(o.z * inv); ob[3] = f2bf(o.w * inv);
            *(us4*)(ctxg + (size_t)(bb * NSEG + row) * CC + h * HD + c4 * 4) = ob;
        }
        __syncthreads();                   // before qs/ks/vs overwrite next head
    }
    __threadfence_block();                 // ctx global writes -> visible in block
    __syncthreads();

    // O-proj: 16x768 = 48 n-tiles over 4 waves, A from ctxg, B=wto [n][k]
    int lane = tid & 63, wv = tid >> 6;
    int l15 = lane & 15, lh = lane >> 4;
    const unsigned short* Arow = ctxg + (size_t)(bb * NSEG + l15) * CC + lh * 8;
    for (int nt_ = wv; nt_ < 48; nt_ += 4) {
        int n0 = nt_ * 16;
        const unsigned short* Brow = wto + (size_t)(n0 + l15) * CC + lh * 8;
        f32x4 acc = {0.f, 0.f, 0.f, 0.f};
        #pragma unroll 4
        for (int k0 = 0; k0 < CC; k0 += 32) {
            short8 a = *(const short8*)(Arow + k0);
            short8 b = *(const short8*)(Brow + k0);
            acc = __builtin_amdgcn_mfma_f32_16x16x32_bf16(a, b, acc, 0, 0, 0);
        }
        #pragma unroll
        for (int r = 0; r < 4; ++r) {
            int drow = lh * 4 + r;
            int col = n0 + l15;
            float v = acc[r] + bo[col] + s_shift[(size_t)(bb * NSEG + drow) * CC + col];
            out[(size_t)(bb * NSEG + drow) * (size_t)(PP * CC) + col] = v;
        }
    }
}

extern "C" void kernel_launch(void* const* d_in, const int* in_sizes, int n_in,
                              void* d_out, int out_size, void* d_ws, size_t ws_size,
                              hipStream_t stream) {
    const float* x    = (const float*)d_in[0];
    const float* w1   = (const float*)d_in[1];
    const float* ln_g = (const float*)d_in[2];
    const float* ln_b = (const float*)d_in[3];
    const float* Wq   = (const float*)d_in[4];
    const float* bq   = (const float*)d_in[5];
    const float* Wk   = (const float*)d_in[6];
    const float* bk   = (const float*)d_in[7];
    const float* Wv   = (const float*)d_in[8];
    const float* bv   = (const float*)d_in[9];
    const float* Wo   = (const float*)d_in[10];
    const float* bo   = (const float*)d_in[11];
    float* out = (float*)d_out;

    float* ws      = (float*)d_ws;
    float* s_shift = ws;                                      // MN f32
    float* qkv     = s_shift + MN;                            // 3*MN f32
    unsigned short* tln  = (unsigned short*)(qkv + 3 * MN);   // MN bf16
    unsigned short* ctxg = tln + MN;                          // MN bf16
    unsigned short* wt   = ctxg + MN;                         // 4*CC*CC bf16

    const unsigned S1 = 3500000u, S2 = 11500000u;

    k1<<<K1_CPY + K1_LN + K1_CVT, 256, 0, stream>>>(x, w1, ln_g, ln_b, Wq, Wk, Wv, Wo,
                                                    s_shift, tln, wt, out, 0u, S1);
    k2<<<K2_CPY + K2_GEMM, 256, 0, stream>>>(tln, wt, bq, bk, bv, qkv, x, out, S1, S2);
    k3<<<K3_CPY + K3_FUSE, 256, 0, stream>>>(qkv, wt + (size_t)3 * CC * CC, bo, s_shift,
                                             ctxg, out, x, S2, W4TOT);
}

// Round 4
// 166.210 us; speedup vs baseline: 1.4804x; 1.4804x over previous
//
#include <hip/hip_runtime.h>
#include <math.h>

typedef __attribute__((ext_vector_type(8))) short short8;
typedef __attribute__((ext_vector_type(4))) float f32x4;
typedef __attribute__((ext_vector_type(4))) unsigned short us4;

constexpr int NSEG = 16;
constexpr int CC   = 768;
constexpr int PP   = 197;
constexpr int NH   = 12;
constexpr int HD   = 64;
constexpr int NT   = 512;
constexpr int MN   = NT * CC;
constexpr float LN_EPS = 1e-5f;

// pass-through copy geometry, in float4 units (p>=1 rows of every token)
constexpr unsigned CPT  = 196 * CC / 4;          // 37632
constexpr unsigned TOK4 = PP * CC / 4;           // 37824
constexpr unsigned ROW4 = CC / 4;                // 192
constexpr unsigned W4TOT = (unsigned)NT * CPT;   // 19267584

__device__ inline unsigned short f2bf(float f) {
    unsigned u = __float_as_uint(f);
    u += 0x7fffu + ((u >> 16) & 1u);
    return (unsigned short)(u >> 16);
}

__device__ inline unsigned cidx(unsigned i) {
    unsigned t = i / CPT;                 // magic-mul
    return i + t * ROW4 + ROW4;
}

// 4-deep unrolled copy: 4 loads in flight before the stores (MLP)
__device__ inline void copy_slice(const float* __restrict__ xf, float* __restrict__ of,
                                  unsigned start, unsigned end,
                                  unsigned gt, unsigned nth) {
    const float4* __restrict__ x4 = (const float4*)xf;
    float4* __restrict__ o4 = (float4*)of;
    unsigned i = start + gt;
    unsigned s1 = nth, s2 = 2 * nth, s3 = 3 * nth, s4 = 4 * nth;
    for (; i + s3 < end; i += s4) {
        unsigned a0 = cidx(i), a1 = cidx(i + s1), a2 = cidx(i + s2), a3 = cidx(i + s3);
        float4 v0 = x4[a0];
        float4 v1 = x4[a1];
        float4 v2 = x4[a2];
        float4 v3 = x4[a3];
        o4[a0] = v0; o4[a1] = v1; o4[a2] = v2; o4[a3] = v3;
    }
    for (; i < end; i += s1) { unsigned a = cidx(i); o4[a] = x4[a]; }
}

// ---------------- 64x64 MFMA bf16 tile, 4 waves, fragments direct from global ----------------
template<bool ADD_RES>
__device__ inline void gemm_tile(const unsigned short* __restrict__ A,   // 512xCC bf16 row-major
                                 const unsigned short* __restrict__ Bt,  // CCxCC bf16, [n][k]
                                 const float* __restrict__ bias,
                                 const float* __restrict__ res,          // 512xCC f32 (if ADD_RES)
                                 float* __restrict__ outp,
                                 int by, int bx, size_t orow) {
    int tid  = threadIdx.x;
    int lane = tid & 63, wv = tid >> 6;
    int wr = wv >> 1, wc = wv & 1;
    int l15 = lane & 15, lh = lane >> 4;
    int m0 = by * 64 + wr * 32;
    int n0 = bx * 64 + wc * 32;
    f32x4 acc[2][2] = {};
    const unsigned short* Ar0 = A  + (size_t)(m0 + l15) * CC + lh * 8;
    const unsigned short* Ar1 = Ar0 + 16 * CC;
    const unsigned short* Br0 = Bt + (size_t)(n0 + l15) * CC + lh * 8;
    const unsigned short* Br1 = Br0 + 16 * CC;
    #pragma unroll 4
    for (int k0 = 0; k0 < CC; k0 += 32) {
        short8 a0 = *(const short8*)(Ar0 + k0);
        short8 a1 = *(const short8*)(Ar1 + k0);
        short8 b0 = *(const short8*)(Br0 + k0);
        short8 b1 = *(const short8*)(Br1 + k0);
        acc[0][0] = __builtin_amdgcn_mfma_f32_16x16x32_bf16(a0, b0, acc[0][0], 0, 0, 0);
        acc[0][1] = __builtin_amdgcn_mfma_f32_16x16x32_bf16(a0, b1, acc[0][1], 0, 0, 0);
        acc[1][0] = __builtin_amdgcn_mfma_f32_16x16x32_bf16(a1, b0, acc[1][0], 0, 0, 0);
        acc[1][1] = __builtin_amdgcn_mfma_f32_16x16x32_bf16(a1, b1, acc[1][1], 0, 0, 0);
    }
    #pragma unroll
    for (int mf = 0; mf < 2; ++mf)
        #pragma unroll
        for (int nf = 0; nf < 2; ++nf)
            #pragma unroll
            for (int r = 0; r < 4; ++r) {
                int row = m0 + mf * 16 + lh * 4 + r;
                int col = n0 + nf * 16 + l15;
                float v = acc[mf][nf][r] + bias[col];
                if (ADD_RES) v += res[(size_t)row * CC + col];
                outp[(size_t)row * orow + col] = v;
            }
}

// ================= K1: shift+LN (512) | weight cvt+transpose (2304) | copy (768) =================
constexpr int K1_LN = NT, K1_CVT = 2304, K1_CPY = 768;
__global__ __launch_bounds__(256) void k1(const float* __restrict__ x, const float* __restrict__ w1,
        const float* __restrict__ g, const float* __restrict__ bln,
        const float* __restrict__ Wq, const float* __restrict__ Wk,
        const float* __restrict__ Wv, const float* __restrict__ Wo,
        float* __restrict__ s_shift, unsigned short* __restrict__ tln,
        unsigned short* __restrict__ wt, float* __restrict__ out,
        unsigned cstart, unsigned cend) {
    __shared__ float smem[32 * 33];
    int bid = blockIdx.x, tid = threadIdx.x;
    if (bid < K1_LN) {
        int r = bid, seg = r & (NSEG - 1);
        float vals[3]; float local = 0.f;
        #pragma unroll
        for (int i = 0; i < 3; ++i) {
            int c = tid + i * 256;
            float v = x[(size_t)r * PP * CC + c];
            if (seg > 0) v += w1[c] * x[(size_t)(r - 1) * PP * CC + c];
            vals[i] = v; local += v;
        }
        smem[tid] = local; __syncthreads();
        for (int off = 128; off > 0; off >>= 1) {
            if (tid < off) smem[tid] += smem[tid + off];
            __syncthreads();
        }
        float mu = smem[0] * (1.0f / CC); __syncthreads();
        float lv = 0.f;
        #pragma unroll
        for (int i = 0; i < 3; ++i) { float d = vals[i] - mu; lv += d * d; }
        smem[tid] = lv; __syncthreads();
        for (int off = 128; off > 0; off >>= 1) {
            if (tid < off) smem[tid] += smem[tid + off];
            __syncthreads();
        }
        float rstd = rsqrtf(smem[0] * (1.0f / CC) + LN_EPS);
        #pragma unroll
        for (int i = 0; i < 3; ++i) {
            int c = tid + i * 256;
            s_shift[(size_t)r * CC + c] = vals[i];
            tln[(size_t)r * CC + c] = f2bf((vals[i] - mu) * rstd * g[c] + bln[c]);
        }
    } else if (bid < K1_LN + K1_CVT) {
        int idx = bid - K1_LN;
        int mat = idx / 576, tile = idx % 576;
        int tr = tile / 24, tc = tile % 24;
        const float* W = mat == 0 ? Wq : mat == 1 ? Wk : mat == 2 ? Wv : Wo;
        int lr = tid >> 3, lc = (tid & 7) * 4;
        float4 v = *(const float4*)(W + (size_t)(tr * 32 + lr) * CC + tc * 32 + lc);
        smem[lr * 33 + lc + 0] = v.x; smem[lr * 33 + lc + 1] = v.y;
        smem[lr * 33 + lc + 2] = v.z; smem[lr * 33 + lc + 3] = v.w;
        __syncthreads();
        int ln_ = tid >> 3, kc = (tid & 7) * 4;
        us4 o;
        #pragma unroll
        for (int j = 0; j < 4; ++j) o[j] = f2bf(smem[(kc + j) * 33 + ln_]);
        *(us4*)(wt + (size_t)mat * CC * CC + (size_t)(tc * 32 + ln_) * CC + tr * 32 + kc) = o;
    } else {
        unsigned cb = bid - (K1_LN + K1_CVT);
        copy_slice(x, out, cstart, cend, cb * 256 + tid, K1_CPY * 256);
    }
}

// ================= K2: QKV MFMA GEMM (288) | copy (1024) =================
constexpr int K2_GEMM = 288, K2_CPY = 1024;
__global__ __launch_bounds__(256) void k2(const unsigned short* __restrict__ tln,
        const unsigned short* __restrict__ wt,
        const float* __restrict__ bq, const float* __restrict__ bk, const float* __restrict__ bv,
        float* __restrict__ qkv,
        const float* __restrict__ x, float* __restrict__ out,
        unsigned cstart, unsigned cend) {
    int bid = blockIdx.x, tid = threadIdx.x;
    if (bid < K2_GEMM) {
        int z = bid / 96, rem = bid % 96;
        int by = rem / 12, bx = rem % 12;
        const unsigned short* Bt = wt + (size_t)z * CC * CC;
        const float* bias = z == 0 ? bq : (z == 1 ? bk : bv);
        float* outp = qkv + (size_t)z * MN;
        gemm_tile<false>(tln, Bt, bias, nullptr, outp, by, bx, CC);
    } else {
        unsigned cb = bid - K2_GEMM;
        copy_slice(x, out, cstart, cend, cb * 256 + tid, K2_CPY * 256);
    }
}

// ================= K3: attention (384) | copy (1024) =================
constexpr int K3_ATT = 32 * NH, K3_CPY = 1024;
__global__ __launch_bounds__(256) void k3(const float* __restrict__ qkv,
        unsigned short* __restrict__ ctxb,
        const float* __restrict__ x, float* __restrict__ out,
        unsigned cstart, unsigned cend) {
    int bid = blockIdx.x, tid = threadIdx.x;
    if (bid < K3_ATT) {
        const float* q = qkv;
        const float* k = qkv + MN;
        const float* v = qkv + 2 * MN;
        int bb = bid / NH, h = bid % NH;
        __shared__ float qs[16][HD], ks[16][HD], vs[16][HD];
        __shared__ float sc[16][17];
        __shared__ float rsum[16];
        for (int i = tid; i < 16 * HD; i += 256) {
            int t = i >> 6, d = i & 63;
            size_t gidx = (size_t)(bb * NSEG + t) * CC + h * HD + d;
            qs[t][d] = q[gidx]; ks[t][d] = k[gidx]; vs[t][d] = v[gidx];
        }
        __syncthreads();
        {
            int t = tid >> 4, s = tid & 15;
            float acc = 0.f;
            #pragma unroll
            for (int d = 0; d < HD; ++d) acc += qs[t][d] * ks[s][d];
            sc[t][s] = acc * 0.125f;
        }
        __syncthreads();
        if (tid < 16) {
            float m = -1e30f;
            #pragma unroll
            for (int s = 0; s < 16; ++s) m = fmaxf(m, sc[tid][s]);
            float sum = 0.f;
            #pragma unroll
            for (int s = 0; s < 16; ++s) { float e = __expf(sc[tid][s] - m); sc[tid][s] = e; sum += e; }
            rsum[tid] = sum;
        }
        __syncthreads();
        for (int i = tid; i < 16 * HD; i += 256) {
            int t = i >> 6, d = i & 63;
            float acc = 0.f;
            #pragma unroll
            for (int s = 0; s < 16; ++s) acc += sc[t][s] * vs[s][d];
            ctxb[(size_t)(bb * NSEG + t) * CC + h * HD + d] = f2bf(acc / rsum[t]);
        }
    } else {
        unsigned cb = bid - K3_ATT;
        copy_slice(x, out, cstart, cend, cb * 256 + tid, K3_CPY * 256);
    }
}

// ================= K4: O-proj GEMM + residual into out[p=0] (96) | copy (1024) =================
constexpr int K4_GEMM = 96, K4_CPY = 1024;
__global__ __launch_bounds__(256) void k4(const unsigned short* __restrict__ ctxb,
        const unsigned short* __restrict__ wto,
        const float* __restrict__ bo, const float* __restrict__ s_shift,
        float* __restrict__ out, const float* __restrict__ x,
        unsigned cstart, unsigned cend) {
    int bid = blockIdx.x, tid = threadIdx.x;
    if (bid < K4_GEMM) {
        int by = bid / 12, bx = bid % 12;
        gemm_tile<true>(ctxb, wto, bo, s_shift, out, by, bx, (size_t)PP * CC);
    } else {
        unsigned cb = bid - K4_GEMM;
        copy_slice(x, out, cstart, cend, cb * 256 + tid, K4_CPY * 256);
    }
}

extern "C" void kernel_launch(void* const* d_in, const int* in_sizes, int n_in,
                              void* d_out, int out_size, void* d_ws, size_t ws_size,
                              hipStream_t stream) {
    const float* x    = (const float*)d_in[0];
    const float* w1   = (const float*)d_in[1];
    const float* ln_g = (const float*)d_in[2];
    const float* ln_b = (const float*)d_in[3];
    const float* Wq   = (const float*)d_in[4];
    const float* bq   = (const float*)d_in[5];
    const float* Wk   = (const float*)d_in[6];
    const float* bk   = (const float*)d_in[7];
    const float* Wv   = (const float*)d_in[8];
    const float* bv   = (const float*)d_in[9];
    const float* Wo   = (const float*)d_in[10];
    const float* bo   = (const float*)d_in[11];
    float* out = (float*)d_out;

    float* ws      = (float*)d_ws;
    float* s_shift = ws;                                      // MN f32
    float* qkv     = s_shift + MN;                            // 3*MN f32
    unsigned short* tln  = (unsigned short*)(qkv + 3 * MN);   // MN bf16
    unsigned short* ctxb = tln + MN;                          // MN bf16
    unsigned short* wt   = ctxb + MN;                         // 4*CC*CC bf16

    const unsigned s0 = 0, s1 = 5400000u, s2 = 10400000u, s3 = 15400000u, s4 = W4TOT;

    k1<<<K1_LN + K1_CVT + K1_CPY, 256, 0, stream>>>(x, w1, ln_g, ln_b, Wq, Wk, Wv, Wo,
                                                    s_shift, tln, wt, out, s0, s1);
    k2<<<K2_GEMM + K2_CPY, 256, 0, stream>>>(tln, wt, bq, bk, bv, qkv, x, out, s1, s2);
    k3<<<K3_ATT + K3_CPY, 256, 0, stream>>>(qkv, ctxb, x, out, s2, s3);
    k4<<<K4_GEMM + K4_CPY, 256, 0, stream>>>(ctxb, wt + (size_t)3 * CC * CC, bo, s_shift,
                                             out, x, s3, s4);
}